// Round 1
// baseline (112.072 us; speedup 1.0000x reference)
//
#include <hip/hip_runtime.h>

// AbsolutePositionExtractor: features[b, s*4 + {0,1,2,3}] =
//   [sin(rad_lat*scale_s), cos(rad_lat*scale_s), sin(rad_lon*scale_s), cos(rad_lon*scale_s)]
// with rad = fl32(deg * fl32(pi/180)) and scale_s = int32(2**s) (JAX int32 wrap:
// s=31 -> -2^31, s>=32 -> 0). Then mask (B bools) and positions (2B floats) = 0.
//
// Streaming-store bound: ~518 MB out. One thread per (point, scale) -> float4.

__global__ __launch_bounds__(256) void posfeat_kernel(const float* __restrict__ ll,
                                                      float4* __restrict__ out,
                                                      int B) {
    const double QHI = 0x1.45F306DC9C883p-3;      // fl64(1/(2*pi))
    const float DEG2RAD = 0.017453292519943295f;  // fl32(pi/180) — matches jax/np deg2rad

    int t = blockIdx.x * 256 + threadIdx.x;
    int total = B * 64;
    if (t >= total) return;
    int b = t >> 6;
    int s = t & 63;

    float4 o;
    if (s >= 32) {
        // int32 wrap: 2**s == 0 for s >= 32 -> angle 0 -> sin=0, cos=1
        o.x = 0.0f; o.y = 1.0f; o.z = 0.0f; o.w = 1.0f;
    } else {
        float2 p = reinterpret_cast<const float2*>(ll)[b];
        float rlat = p.x * DEG2RAD;   // single IEEE f32 mul, bit-identical to reference
        float rlon = p.y * DEG2RAD;
        // int32 wrap semantics: (int)(1u<<31) == -2^31; exact as double (power of 2)
        double scale = (double)(int)(1u << s);
        double xla = (double)rlat * scale;   // exact: 24-bit mantissa * 2^k
        double xlo = (double)rlon * scale;
        // revolutions = frac(x / 2pi); |x| <= ~2^33 so plain double reduction gives
        // abs error <= ~2^-23 rev -> sin abs error <= ~1.3e-6 (threshold is 2e-2)
        double fa = xla * QHI;  fa -= floor(fa);
        double fb = xlo * QHI;  fb -= floor(fb);
        float ra = (float)fa, rb = (float)fb;
        o.x = __builtin_amdgcn_sinf(ra);   // v_sin_f32: sin(2*pi*ra)
        o.y = __builtin_amdgcn_cosf(ra);   // v_cos_f32: cos(2*pi*ra)
        o.z = __builtin_amdgcn_sinf(rb);
        o.w = __builtin_amdgcn_cosf(rb);
    }
    out[t] = o;   // wave of 64 lanes writes 1 KB contiguous, fully coalesced
}

__global__ __launch_bounds__(256) void zero_kernel(float* __restrict__ z, long long n) {
    long long t = ((long long)blockIdx.x * 256 + threadIdx.x) * 4;
    if (t + 4 <= n) {
        *reinterpret_cast<float4*>(z + t) = make_float4(0.f, 0.f, 0.f, 0.f);
    } else {
        for (long long i = t; i < n; ++i) z[i] = 0.f;
    }
}

extern "C" void kernel_launch(void* const* d_in, const int* in_sizes, int n_in,
                              void* d_out, int out_size, void* d_ws, size_t ws_size,
                              hipStream_t stream) {
    const float* ll = (const float*)d_in[0];
    float* out = (float*)d_out;
    int B = in_sizes[0] / 2;

    int total = B * 64;                 // one thread per (point, scale), 32M threads
    int grid = (total + 255) / 256;
    posfeat_kernel<<<grid, 256, 0, stream>>>(ll, (float4*)out, B);

    // mask [B] + positions [2B] -> zeros, appended after features (B*256 floats)
    long long rest = (long long)out_size - (long long)B * 256;
    if (rest > 0) {
        float* z = out + (long long)B * 256;
        int g2 = (int)((rest + 1023) / 1024);   // 256 threads * 4 floats each
        zero_kernel<<<g2, 256, 0, stream>>>(z, rest);
    }
}

// Round 3
// 99.450 us; speedup vs baseline: 1.1269x; 1.1269x over previous
//
#include <hip/hip_runtime.h>

// AbsolutePositionExtractor: features[b, s*4 + {0..3}] =
//   [sin(rad_lat*scale_s), cos(rad_lat*scale_s), sin(rad_lon*scale_s), cos(rad_lon*scale_s)]
// rad = fl32(deg * fl32(pi/180)); scale_s = int32(2**s) (JAX int32 wrap:
// s=31 -> -2^31, s>=32 -> 0 -> sin=0,cos=1). Then mask+positions = zeros.
//
// Streaming-store bound (~522 MB). Work unit u in [0, B*32): b=u>>5, s=u&31.
// Each unit writes the computed float4 at (b*64+s) AND the constant float4 at
// (b*64+s+32) -- removes the s>=32 wave divergence, 2 stores/iter for MLP.
// Units >= B*32 map to the zero tail (mask + positions). Grid-stride, 4096 blocks.

typedef float f32x4 __attribute__((ext_vector_type(4)));  // native vector: OK for nontemporal builtin

__global__ __launch_bounds__(256) void posfeat_kernel(const float* __restrict__ ll,
                                                      f32x4* __restrict__ out,
                                                      int B, long long n4) {
    const double QHI = 0x1.45F306DC9C883p-3;      // fl64(1/(2*pi))
    const float DEG2RAD = 0.017453292519943295f;  // fl32(pi/180), matches np/jax deg2rad

    const long long featUnits = (long long)B * 32;
    const long long zeroUnits = n4 - (long long)B * 64;   // float4s after features
    const long long totalUnits = featUnits + zeroUnits;
    const long long stride = (long long)gridDim.x * 256;
    const f32x4 CONST4 = {0.f, 1.f, 0.f, 1.f};
    const f32x4 ZERO4 = {0.f, 0.f, 0.f, 0.f};

    for (long long u = (long long)blockIdx.x * 256 + threadIdx.x; u < totalUnits; u += stride) {
        if (u < featUnits) {
            int b = (int)(u >> 5);
            int s = (int)(u & 31);
            float2 p = reinterpret_cast<const float2*>(ll)[b];
            float rlat = p.x * DEG2RAD;   // single IEEE f32 mul — bit-identical to reference
            float rlon = p.y * DEG2RAD;
            // int32 wrap: (int)(1u<<31) == -2^31; exact as double (power of two)
            double scale = (double)(int)(1u << s);
            double xla = (double)rlat * scale;   // exact: 24-bit mantissa * 2^k
            double xlo = (double)rlon * scale;
            // revolutions = frac(x/2pi); |x| <= ~2^33, double keeps abs err <= ~2^-23 rev
            double fa = xla * QHI;  fa -= floor(fa);
            double fb = xlo * QHI;  fb -= floor(fb);
            float ra = (float)fa, rb = (float)fb;
            f32x4 o;
            o.x = __builtin_amdgcn_sinf(ra);   // v_sin_f32: sin(2*pi*x)
            o.y = __builtin_amdgcn_cosf(ra);
            o.z = __builtin_amdgcn_sinf(rb);
            o.w = __builtin_amdgcn_cosf(rb);
            long long base = ((long long)b << 6) + s;
            __builtin_nontemporal_store(o, &out[base]);           // scales 0..31
            __builtin_nontemporal_store(CONST4, &out[base + 32]); // scales 32..63: sin=0,cos=1
        } else {
            long long idx4 = (long long)B * 64 + (u - featUnits);
            __builtin_nontemporal_store(ZERO4, &out[idx4]);       // mask + positions = 0
        }
    }
}

__global__ void tail_zero_kernel(float* __restrict__ z, int n) {
    // scalar tail if out_size % 4 != 0 (not expected for B=500K; safety only)
    int t = threadIdx.x;
    if (t < n) z[t] = 0.f;
}

extern "C" void kernel_launch(void* const* d_in, const int* in_sizes, int n_in,
                              void* d_out, int out_size, void* d_ws, size_t ws_size,
                              hipStream_t stream) {
    const float* ll = (const float*)d_in[0];
    float* out = (float*)d_out;
    int B = in_sizes[0] / 2;

    long long n4 = (long long)out_size >> 2;
    posfeat_kernel<<<4096, 256, 0, stream>>>(ll, (f32x4*)out, B, n4);

    int tail = out_size & 3;
    if (tail) {
        tail_zero_kernel<<<1, 64, 0, stream>>>(out + ((long long)out_size - tail), tail);
    }
}